// Round 3
// baseline (247.400 us; speedup 1.0000x reference)
//
#include <hip/hip_runtime.h>

// NeighbourCovariance: per vertex v, gather K=40 neighbors, weight features by
// exp(-10*distsq), compute per-feature weighted mean (C=3) and covariance (3x3).
// Output layout per vertex: [cov (F*9)] ++ [means (F*3)] = 384 floats.
//
// R5: VALU-issue attack. R4 post-mortem showed VALU busy-time constant at
// ~57 us across R2->R4 (52%x112 = 60%x95) -> phase 2 instruction count is the
// floor. Change: precompute per-pair coordinate moments in phase 1
// (w, wx, wy, wz, wxx, wxy, wxz, wyy, wyz, wzz), so phase 2 collapses to
// 5 packed-FP32 FMAs (v_pk_fma_f32) against a broadcast feature value:
//   (wsum,m0)+=(w,wx)*feat   (m1,m2)+=(wy,wz)*feat   (s00,s01)+=(wxx,wxy)*feat
//   (s02,s11)+=(wxz,wyy)*feat (s12,s22)+=(wyz,wzz)*feat
// Pairs come directly from ds_read_b128 destinations (even-aligned VGPR pairs)
// so no packing moves. ~17 VALU/iter -> ~7-8.
//
// Phases otherwise as R4: NT loads of nidx/distsq streams; LDS-staged output
// written back as coalesced 16B NT stores.
//
// LDS: s_a 5120 + s_b 5120 + s_c 2560 + s_joff 1280 + s_out4 12288 = 26368 B
//      -> 6 blocks/CU (158 KB of 160 KB), 24 waves/CU.

constexpr int K = 40;
constexpr int C = 3;
constexpr int F = 32;
constexpr float EPS = 1e-3f;
constexpr float DIST_SCALE = 10.0f;
constexpr int OUT_PER_V = F * C * C + F * C; // 384
constexpr int VPB = 8;                        // vertices per 256-thread block
constexpr int PAIRS = VPB * K;                // 320
constexpr int OUT_DW = VPB * OUT_PER_V;       // 3072 dwords staged per block
constexpr int OUT_F4 = OUT_DW / 4;            // 768 float4 per block

typedef float floatx4 __attribute__((ext_vector_type(4)));  // nt-store compatible
typedef float v2f     __attribute__((ext_vector_type(2)));  // v_pk_fma_f32 operand

__global__ __launch_bounds__(256) void neighcov_kernel(
    const float* __restrict__ coords,    // V x 3
    const float* __restrict__ distsq,    // V x K
    const float* __restrict__ features,  // V x F
    const int*   __restrict__ nidx,      // V x K
    float* __restrict__ out,             // V x 384
    int V)
{
    __shared__ float4  s_a[PAIRS];      // (w,   wx,  wy,  wz ) per (v,k)
    __shared__ float4  s_b[PAIRS];      // (wxx, wxy, wxz, wyy)
    __shared__ v2f     s_c[PAIRS];      // (wyz, wzz)
    __shared__ int     s_joff[PAIRS];   // j*F element offset into features
    __shared__ floatx4 s_out4[OUT_F4];  // staged output (16B-aligned)

    const int tid   = threadIdx.x;
    const int vbase = blockIdx.x * VPB;
    const long long total_pairs = (long long)V * K;

    // ---- Phase 1: stage weighted coordinate moments, 320 pairs ----
    #pragma unroll
    for (int p = tid; p < PAIRS; p += 256) {
        const long long gp = (long long)vbase * K + p;
        int idx = -1;
        float d = 0.f;
        if (gp < total_pairs) {
            idx = __builtin_nontemporal_load(nidx + gp);    // coalesced, single-use
            d   = __builtin_nontemporal_load(distsq + gp);  // coalesced, single-use
        }
        const bool valid = (idx >= 0);
        const int j = valid ? idx : 0;
        const float w = valid ? __expf(-DIST_SCALE * d) : 0.f;  // w==0 encodes invalid
        const float x = coords[(size_t)j * 3 + 0];
        const float y = coords[(size_t)j * 3 + 1];
        const float z = coords[(size_t)j * 3 + 2];
        const float wx = w * x, wy = w * y, wz = w * z;
        s_a[p] = make_float4(w, wx, wy, wz);
        s_b[p] = make_float4(wx * x, wx * y, wx * z, wy * y);
        s_c[p] = (v2f){wy * z, wz * z};
        s_joff[p] = j * F;
    }
    __syncthreads();

    // ---- Phase 2: one lane per (vertex, feature); 5 pk_fma per neighbor ----
    const int f    = tid & (F - 1);
    const int vloc = tid >> 5;

    const v2f* a2 = (const v2f*)(s_a + vloc * K);  // pairs (w,wx) (wy,wz)
    const v2f* b2 = (const v2f*)(s_b + vloc * K);  // pairs (wxx,wxy) (wxz,wyy)
    const v2f* c2 = s_c + vloc * K;                // pair  (wyz,wzz)
    const int* jp = s_joff + vloc * K;

    v2f acc0 = {0.f, 0.f};  // (wsum, m0)
    v2f acc1 = {0.f, 0.f};  // (m1,   m2)
    v2f acc2 = {0.f, 0.f};  // (s00,  s01)
    v2f acc3 = {0.f, 0.f};  // (s02,  s11)
    v2f acc4 = {0.f, 0.f};  // (s12,  s22)

    #pragma unroll 8
    for (int k = 0; k < K; ++k) {
        const v2f a_lo = a2[2 * k];      // broadcast LDS reads (merge to b128)
        const v2f a_hi = a2[2 * k + 1];
        const v2f b_lo = b2[2 * k];
        const v2f b_hi = b2[2 * k + 1];
        const v2f cc   = c2[k];
        const int jo   = jp[k];
        const float feat = features[jo + f];  // coalesced 128B row gather
        const v2f fv = {feat, feat};
        acc0 = __builtin_elementwise_fma(a_lo, fv, acc0);
        acc1 = __builtin_elementwise_fma(a_hi, fv, acc1);
        acc2 = __builtin_elementwise_fma(b_lo, fv, acc2);
        acc3 = __builtin_elementwise_fma(b_hi, fv, acc3);
        acc4 = __builtin_elementwise_fma(cc,   fv, acc4);
    }

    const float wsum = acc0.x, m0 = acc0.y, m1 = acc1.x, m2 = acc1.y;
    const float s00 = acc2.x, s01 = acc2.y, s02 = acc3.x;
    const float s11 = acc3.y, s12 = acc4.x, s22 = acc4.y;

    const float inv = 1.f / (wsum + EPS);
    const float mu0 = m0 * inv, mu1 = m1 * inv, mu2 = m2 * inv;
    const float c00 = s00 * inv - mu0 * mu0;
    const float c01 = s01 * inv - mu0 * mu1;
    const float c02 = s02 * inv - mu0 * mu2;
    const float c11 = s11 * inv - mu1 * mu1;
    const float c12 = s12 * inv - mu1 * mu2;
    const float c22 = s22 * inv - mu2 * mu2;

    // Stage results in LDS. Strides 9 and 3 are odd -> per-half-wave bank
    // permutation, 2 lanes/bank max (free).
    float* s_out = (float*)s_out4;
    float* so = s_out + vloc * OUT_PER_V + f * 9;
    so[0] = c00; so[1] = c01; so[2] = c02;
    so[3] = c01; so[4] = c11; so[5] = c12;
    so[6] = c02; so[7] = c12; so[8] = c22;
    float* sm = s_out + vloc * OUT_PER_V + F * 9 + f * 3;
    sm[0] = mu0; sm[1] = mu1; sm[2] = mu2;

    __syncthreads();

    // ---- Phase 3: coalesced non-temporal 16B writeback ----
    const int rem_v  = V - vbase;  // >= 1
    const int lim_f4 = (rem_v >= VPB) ? OUT_F4 : rem_v * (OUT_PER_V / 4);
    floatx4* o4 = (floatx4*)(out + (size_t)vbase * OUT_PER_V);
    #pragma unroll
    for (int g = tid; g < OUT_F4; g += 256) {
        if (g < lim_f4) {
            __builtin_nontemporal_store(s_out4[g], o4 + g);  // contiguous b128 LDS read
        }
    }
}

extern "C" void kernel_launch(void* const* d_in, const int* in_sizes, int n_in,
                              void* d_out, int out_size, void* d_ws, size_t ws_size,
                              hipStream_t stream) {
    const float* coords   = (const float*)d_in[0];
    const float* distsq   = (const float*)d_in[1];
    const float* features = (const float*)d_in[2];
    const int*   nidx     = (const int*)d_in[3];
    float* out = (float*)d_out;

    const int V = in_sizes[0] / C;            // coordinates is V x 3
    const int blocks = (V + VPB - 1) / VPB;   // 8 vertices per 256-thread block

    neighcov_kernel<<<blocks, 256, 0, stream>>>(coords, distsq, features, nidx, out, V);
}